// Round 17
// baseline (140.742 us; speedup 1.0000x reference)
//
#include <hip/hip_runtime.h>
#include <hip/hip_fp16.h>

typedef _Float16 f16x8 __attribute__((ext_vector_type(8)));
typedef float    f32x4 __attribute__((ext_vector_type(4)));

constexpr int DIN = 32;
constexpr int DH  = 64;
constexpr int NBSHIFT = 8;            // 256 nodes per coarse bucket
constexpr int TILE_A  = 4096;         // edges per tile
constexpr int FB_CAP  = 6144;         // fillB LDS sort capacity

// ========== k_prep: per-tile hist -> CH (atomic merge), x->fp16, W-frags ====
__global__ __launch_bounds__(256) void k_prep(
    const int* __restrict__ dst, const float2* __restrict__ x2,
    __half2* __restrict__ xh,
    const float* __restrict__ w1_rel, const float* __restrict__ w1_root,
    const float* __restrict__ w2_rel, const float* __restrict__ w2_root,
    __half* __restrict__ wf1, __half* __restrict__ wf2,
    int* __restrict__ ch, int E, int n2, int nbuckets) {
  __shared__ int hist[512];
  int tid = threadIdx.x, b = blockIdx.x;
  long long t0 = (long long)b * TILE_A;
  int cnt = (int)min((long long)TILE_A, (long long)E - t0);
  if (cnt < 0) cnt = 0;
  for (int i = tid; i < 512; i += 256) hist[i] = 0;
  __syncthreads();
  for (int r = tid; r < cnt; r += 256)
    atomicAdd(&hist[dst[t0 + r] >> NBSHIFT], 1);
  __syncthreads();
  for (int i = tid; i < nbuckets; i += 256)
    if (hist[i]) atomicAdd(&ch[i], hist[i]);
  for (int i = b * 256 + tid; i < n2; i += gridDim.x * 256) {
    float2 v = x2[i];
    xh[i] = __floats2half2_rn(v.x, v.y);
  }
  if (b == 1) {                       // W1 A-frags: k<32 root, k>=32 rel
    for (int u = tid; u < 512; u += 256) {
      int lane = u & 63, kt = (u >> 6) & 1, mt = u >> 7;
      int outc = 16 * mt + (lane & 15);
      int kb = 32 * kt + (lane >> 4) * 8;
      union { uint4 q; __half h[8]; } w;
#pragma unroll
      for (int j = 0; j < 8; ++j) {
        int k = kb + j;
        float wv = (k < 32) ? w1_root[k * DH + outc] : w1_rel[(k - 32) * DH + outc];
        w.h[j] = __float2half(wv);
      }
      *(uint4*)(wf1 + (size_t)u * 8) = w.q;
    }
  } else if (b == 2) {                // W2 A-frags: k<64 rel, k>=64 root
    for (int u = tid; u < 1024; u += 256) {
      int lane = u & 63, kt = (u >> 6) & 3, mt = u >> 8;
      int outc = 16 * mt + (lane & 15);
      int kb = 32 * kt + (lane >> 4) * 8;
      union { uint4 q; __half h[8]; } w;
#pragma unroll
      for (int j = 0; j < 8; ++j) {
        int k = kb + j;
        float wv = (k < 64) ? w2_rel[k * DH + outc] : w2_root[(k - 64) * DH + outc];
        w.h[j] = __float2half(wv);
      }
      *(uint4*)(wf2 + (size_t)u * 8) = w.q;
    }
  }
}

// ========== k_cscan: exclusive scan of CH =====================
__global__ __launch_bounds__(256) void k_cscan(
    const int* __restrict__ ch, int* __restrict__ cb, int* __restrict__ bcur,
    int nbuckets, int E) {
  __shared__ int ts[256];
  int tid = threadIdx.x;
  int i0 = tid * 2, i1 = i0 + 1;
  int v0 = (i0 < nbuckets) ? ch[i0] : 0;
  int v1 = (i1 < nbuckets) ? ch[i1] : 0;
  int s = v0 + v1;
  ts[tid] = s;
  __syncthreads();
  for (int off = 1; off < 256; off <<= 1) {
    int val = (tid >= off) ? ts[tid - off] : 0;
    __syncthreads();
    ts[tid] += val;
    __syncthreads();
  }
  int ex = ts[tid] - s;
  if (i0 < nbuckets) { cb[i0] = ex;      bcur[i0] = ex; }
  if (i1 < nbuckets) { cb[i1] = ex + v0; bcur[i1] = ex + v0; }
  if (tid == 255) cb[nbuckets] = E;
}

// ========== k_binA: LDS-sorted coarse binning (round-13 proven) =============
__global__ __launch_bounds__(256) void k_binA(
    const int* __restrict__ src, const int* __restrict__ dst,
    int* __restrict__ bcur, unsigned* __restrict__ bin,
    int E, int nbuckets) {
  __shared__ int hist[512];
  __shared__ int lbase[512];
  __shared__ int gbase[512];
  __shared__ int ts[256];
  __shared__ unsigned lsort[TILE_A];
  __shared__ unsigned short lbuck[TILE_A];
  long long t0 = (long long)blockIdx.x * TILE_A;
  int cnt = (int)min((long long)TILE_A, (long long)E - t0);
  for (int i = threadIdx.x; i < 512; i += 256) hist[i] = 0;
  __syncthreads();
  unsigned pk[TILE_A / 256];
  int bo[TILE_A / 256];
#pragma unroll
  for (int q = 0; q < TILE_A / 256; ++q) {
    int r = (int)threadIdx.x + q * 256;
    if (r < cnt) {
      int d = dst[t0 + r];
      int s = src[t0 + r];
      int b = d >> NBSHIFT;
      int off = atomicAdd(&hist[b], 1);
      pk[q] = ((unsigned)(d & 255) << 17) | (unsigned)s;
      bo[q] = (b << 16) | off;
    }
  }
  __syncthreads();
  {
    int i0 = threadIdx.x * 2, i1 = i0 + 1;
    int v0 = hist[i0], v1 = hist[i1];
    int s2 = v0 + v1;
    ts[threadIdx.x] = s2;
    __syncthreads();
    for (int off = 1; off < 256; off <<= 1) {
      int val = (threadIdx.x >= off) ? ts[threadIdx.x - off] : 0;
      __syncthreads();
      ts[threadIdx.x] += val;
      __syncthreads();
    }
    int ex = ts[threadIdx.x] - s2;
    lbase[i0] = ex;
    lbase[i1] = ex + v0;
    gbase[i0] = v0 ? atomicAdd(&bcur[i0], v0) : 0;
    gbase[i1] = v1 ? atomicAdd(&bcur[i1], v1) : 0;
  }
  __syncthreads();
#pragma unroll
  for (int q = 0; q < TILE_A / 256; ++q) {
    int r = (int)threadIdx.x + q * 256;
    if (r < cnt) {
      int b = bo[q] >> 16, off = bo[q] & 0xFFFF;
      int li = lbase[b] + off;
      lsort[li] = pk[q];
      lbuck[li] = (unsigned short)b;
    }
  }
  __syncthreads();
  for (int i = threadIdx.x; i < cnt; i += 256) {
    int b = lbuck[i];
    bin[gbase[b] + (i - lbase[b])] = lsort[i];
  }
}

// ========== k_fillB: fine counting sort -> rp, ssrc (coalesced) =============
__global__ __launch_bounds__(256) void k_fillB(
    const unsigned* __restrict__ bin, const int* __restrict__ cb,
    int* __restrict__ rp, int* __restrict__ ssrc, int n, int E) {
  __shared__ int deg[256];
  __shared__ int ts[256];
  __shared__ int cur[256];
  __shared__ int lsort[FB_CAP];
  int b = blockIdx.x;
  int tid = threadIdx.x;
  int nbase = b << NBSHIFT;
  int nn = min(256, n - nbase);
  int ebeg = cb[b], eend = cb[b + 1];
  int cnt = eend - ebeg;
  deg[tid] = 0;
  __syncthreads();
  for (int e = ebeg + tid; e < eend; e += 256)
    atomicAdd(&deg[bin[e] >> 17], 1);
  __syncthreads();
  int d = deg[tid];
  ts[tid] = d;
  __syncthreads();
  for (int off = 1; off < 256; off <<= 1) {
    int val = (tid >= off) ? ts[tid - off] : 0;
    __syncthreads();
    ts[tid] += val;
    __syncthreads();
  }
  int pref = ts[tid] - d;
  if (tid < nn) rp[nbase + tid] = ebeg + pref;
  if (b == 0 && tid == 0) rp[n] = E;
  cur[tid] = pref;
  __syncthreads();
  if (cnt <= FB_CAP) {
    for (int e = ebeg + tid; e < eend; e += 256) {
      unsigned u = bin[e];
      int pos = atomicAdd(&cur[u >> 17], 1);
      lsort[pos] = (int)(u & 0x1FFFF);
    }
    __syncthreads();
    for (int i = tid; i < cnt; i += 256)
      ssrc[ebeg + i] = lsort[i];      // coalesced
  } else {                            // pathological skew fallback
    for (int e = ebeg + tid; e < eend; e += 256) {
      unsigned u = bin[e];
      int pos = atomicAdd(&cur[u >> 17], 1);
      ssrc[ebeg + pos] = (int)(u & 0x1FFFF);
    }
  }
}

// ========== k_l1fused: gather(LDS) + MFMA (round-13 proven, 1563 blocks) ====
__global__ __launch_bounds__(256) void k_l1fused(
    const _Float16* __restrict__ X, const int* __restrict__ rp,
    const int* __restrict__ ssrc, const _Float16* __restrict__ WF,
    const float* __restrict__ b1, _Float16* __restrict__ H1, int n) {
  __shared__ _Float16 sagg[64][40];
  int tid = threadIdx.x;
  int nl = tid >> 2;
  int unit = tid & 3;
  int nodeg = blockIdx.x * 64 + nl;
  {
    f16x8 accA = (f16x8)(_Float16)0.0f;
    f16x8 accB = (f16x8)(_Float16)0.0f;
    if (nodeg < n) {
      int beg = rp[nodeg], end = rp[nodeg + 1];
      const f16x8* fx = (const f16x8*)X;
      int e = beg;
      for (; e + 7 < end; e += 8) {
        int s0 = ssrc[e],     s1 = ssrc[e + 1], s2 = ssrc[e + 2], s3 = ssrc[e + 3];
        int s4 = ssrc[e + 4], s5 = ssrc[e + 5], s6 = ssrc[e + 6], s7 = ssrc[e + 7];
        f16x8 v0 = fx[(size_t)s0 * 4 + unit];
        f16x8 v1 = fx[(size_t)s1 * 4 + unit];
        f16x8 v2 = fx[(size_t)s2 * 4 + unit];
        f16x8 v3 = fx[(size_t)s3 * 4 + unit];
        f16x8 v4 = fx[(size_t)s4 * 4 + unit];
        f16x8 v5 = fx[(size_t)s5 * 4 + unit];
        f16x8 v6 = fx[(size_t)s6 * 4 + unit];
        f16x8 v7 = fx[(size_t)s7 * 4 + unit];
        accA += v0; accB += v1; accA += v2; accB += v3;
        accA += v4; accB += v5; accA += v6; accB += v7;
      }
      for (; e + 1 < end; e += 2) {
        f16x8 v0 = fx[(size_t)ssrc[e] * 4 + unit];
        f16x8 v1 = fx[(size_t)ssrc[e + 1] * 4 + unit];
        accA += v0; accB += v1;
      }
      if (e < end) accA += fx[(size_t)ssrc[e] * 4 + unit];
    }
    *(f16x8*)&sagg[nl][unit * 8] = accA + accB;
  }
  __syncthreads();
  int lane = tid & 63;
  int w = tid >> 6;
  int nl16 = w * 16 + (lane & 15);
  int node = blockIdx.x * 64 + nl16;
  int nodeld = min(node, n - 1);
  f16x8 bf0 = *(const f16x8*)(X + (size_t)nodeld * 32 + (lane >> 4) * 8);
  f16x8 bf1 = *(const f16x8*)&sagg[nl16][(lane >> 4) * 8];
  const f16x8* ap = (const f16x8*)WF + lane;
  f32x4 acc[4];
#pragma unroll
  for (int mt = 0; mt < 4; ++mt) acc[mt] = (f32x4)(0.f);
#pragma unroll
  for (int mt = 0; mt < 4; ++mt) {
    acc[mt] = __builtin_amdgcn_mfma_f32_16x16x32_f16(ap[(mt * 2 + 0) * 64], bf0, acc[mt], 0, 0, 0);
    acc[mt] = __builtin_amdgcn_mfma_f32_16x16x32_f16(ap[(mt * 2 + 1) * 64], bf1, acc[mt], 0, 0, 0);
  }
  if (node >= n) return;
  int jb = (lane >> 4) * 4;
  _Float16* op = H1 + (size_t)node * 64 + jb;
#pragma unroll
  for (int mt = 0; mt < 4; ++mt) {
    f32x4 vb = *(const f32x4*)(b1 + 16 * mt + jb);
    union { uint2 u2; _Float16 h[4]; } pko;
#pragma unroll
    for (int r = 0; r < 4; ++r)
      pko.h[r] = (_Float16)fmaxf(acc[mt][r] + vb[r], 0.f);
    *(uint2*)(op + 16 * mt) = pko.u2;
  }
}

// ========== k_l2fused (round-13 proven) =====================================
__global__ __launch_bounds__(256) void k_l2fused(
    const _Float16* __restrict__ H1, const int* __restrict__ rp,
    const int* __restrict__ ssrc, const _Float16* __restrict__ WF,
    const float* __restrict__ b2, const float* __restrict__ w3rel,
    const float* __restrict__ w3root,
    float* __restrict__ S, float* __restrict__ T, int n) {
  __shared__ _Float16 sagg[64][72];
  int tid = threadIdx.x;
  int nl = tid >> 2;
  int u0 = tid & 3;
  int nodeg = blockIdx.x * 64 + nl;
  {
    f16x8 aA = (f16x8)(_Float16)0.0f, aB = (f16x8)(_Float16)0.0f;
    f16x8 cA = (f16x8)(_Float16)0.0f, cB = (f16x8)(_Float16)0.0f;
    if (nodeg < n) {
      int beg = rp[nodeg], end = rp[nodeg + 1];
      const f16x8* fh = (const f16x8*)H1;
      int e = beg;
      for (; e + 7 < end; e += 8) {
        int s0 = ssrc[e],     s1 = ssrc[e + 1], s2 = ssrc[e + 2], s3 = ssrc[e + 3];
        int s4 = ssrc[e + 4], s5 = ssrc[e + 5], s6 = ssrc[e + 6], s7 = ssrc[e + 7];
        f16x8 a0 = fh[(size_t)s0 * 8 + u0];
        f16x8 c0 = fh[(size_t)s0 * 8 + u0 + 4];
        f16x8 a1 = fh[(size_t)s1 * 8 + u0];
        f16x8 c1 = fh[(size_t)s1 * 8 + u0 + 4];
        f16x8 a2 = fh[(size_t)s2 * 8 + u0];
        f16x8 c2 = fh[(size_t)s2 * 8 + u0 + 4];
        f16x8 a3 = fh[(size_t)s3 * 8 + u0];
        f16x8 c3 = fh[(size_t)s3 * 8 + u0 + 4];
        f16x8 a4 = fh[(size_t)s4 * 8 + u0];
        f16x8 c4 = fh[(size_t)s4 * 8 + u0 + 4];
        f16x8 a5 = fh[(size_t)s5 * 8 + u0];
        f16x8 c5 = fh[(size_t)s5 * 8 + u0 + 4];
        f16x8 a6 = fh[(size_t)s6 * 8 + u0];
        f16x8 c6 = fh[(size_t)s6 * 8 + u0 + 4];
        f16x8 a7 = fh[(size_t)s7 * 8 + u0];
        f16x8 c7 = fh[(size_t)s7 * 8 + u0 + 4];
        aA += a0; cA += c0; aB += a1; cB += c1;
        aA += a2; cA += c2; aB += a3; cB += c3;
        aA += a4; cA += c4; aB += a5; cB += c5;
        aA += a6; cA += c6; aB += a7; cB += c7;
      }
      for (; e + 1 < end; e += 2) {
        int s0 = ssrc[e], s1 = ssrc[e + 1];
        aA += fh[(size_t)s0 * 8 + u0];
        cA += fh[(size_t)s0 * 8 + u0 + 4];
        aB += fh[(size_t)s1 * 8 + u0];
        cB += fh[(size_t)s1 * 8 + u0 + 4];
      }
      if (e < end) {
        int s0 = ssrc[e];
        aA += fh[(size_t)s0 * 8 + u0];
        cA += fh[(size_t)s0 * 8 + u0 + 4];
      }
    }
    *(f16x8*)&sagg[nl][u0 * 8] = aA + aB;
    *(f16x8*)&sagg[nl][(u0 + 4) * 8] = cA + cB;
  }
  __syncthreads();
  int lane = tid & 63;
  int w = tid >> 6;
  int nl16 = w * 16 + (lane & 15);
  int node = blockIdx.x * 64 + nl16;
  int nodeld = min(node, n - 1);
  f16x8 bf[4];
  bf[0] = *(const f16x8*)&sagg[nl16][(lane >> 4) * 8];
  bf[1] = *(const f16x8*)&sagg[nl16][32 + (lane >> 4) * 8];
  bf[2] = *(const f16x8*)(H1 + (size_t)nodeld * 64 + (lane >> 4) * 8);
  bf[3] = *(const f16x8*)(H1 + (size_t)nodeld * 64 + 32 + (lane >> 4) * 8);
  const f16x8* ap = (const f16x8*)WF + lane;
  f32x4 acc[4];
#pragma unroll
  for (int mt = 0; mt < 4; ++mt) acc[mt] = (f32x4)(0.f);
#pragma unroll
  for (int mt = 0; mt < 4; ++mt)
#pragma unroll
    for (int kt = 0; kt < 4; ++kt)
      acc[mt] = __builtin_amdgcn_mfma_f32_16x16x32_f16(
          ap[(mt * 4 + kt) * 64], bf[kt], acc[mt], 0, 0, 0);
  int jb = (lane >> 4) * 4;
  float s = 0.f, t = 0.f;
#pragma unroll
  for (int mt = 0; mt < 4; ++mt) {
    f32x4 vb = *(const f32x4*)(b2 + 16 * mt + jb);
    f32x4 vr = *(const f32x4*)(w3rel + 16 * mt + jb);
    f32x4 vt = *(const f32x4*)(w3root + 16 * mt + jb);
#pragma unroll
    for (int r = 0; r < 4; ++r) {
      float h = fmaxf(acc[mt][r] + vb[r], 0.f);
      s = fmaf(h, vr[r], s);
      t = fmaf(h, vt[r], t);
    }
  }
  s += __shfl_xor(s, 16); s += __shfl_xor(s, 32);
  t += __shfl_xor(t, 16); t += __shfl_xor(t, 32);
  if (lane < 16 && node < n) { S[node] = s; T[node] = t; }
}

// ========== k_final (round-13 proven) =======================================
__global__ __launch_bounds__(256) void k_final(
    const float* __restrict__ sv, const int* __restrict__ rp,
    const int* __restrict__ ssrc, const float* __restrict__ T,
    const float* __restrict__ b3, float* __restrict__ out, int n) {
  int t = blockIdx.x * 256 + threadIdx.x;
  int node = t >> 2;
  int l = t & 3;
  if (node >= n) return;
  int beg = rp[node], end = rp[node + 1];
  float a = 0.f;
  for (int e = beg + l; e < end; e += 4) a += sv[ssrc[e]];
  a += __shfl_xor(a, 1);
  a += __shfl_xor(a, 2);
  if (l == 0) out[node] = a + b3[0] + T[node];
}

// ===================== launch =====================

extern "C" void kernel_launch(void* const* d_in, const int* in_sizes, int n_in,
                              void* d_out, int out_size, void* d_ws, size_t ws_size,
                              hipStream_t stream) {
  const float* x       = (const float*)d_in[0];
  const float* w1_rel  = (const float*)d_in[1];
  const float* b1      = (const float*)d_in[2];
  const float* w1_root = (const float*)d_in[3];
  const float* w2_rel  = (const float*)d_in[4];
  const float* b2      = (const float*)d_in[5];
  const float* w2_root = (const float*)d_in[6];
  const float* w3_rel  = (const float*)d_in[7];
  const float* b3      = (const float*)d_in[8];
  const float* w3_root = (const float*)d_in[9];
  const int*   edge    = (const int*)d_in[10];

  const int n = in_sizes[0] / DIN;        // 100000 (< 2^17 for packing)
  const int E = in_sizes[10] / 2;         // 1600000
  const int* src = edge;
  const int* dst = edge + E;

  _Float16* XH = (_Float16*)d_ws;                     // n*32 halfs
  _Float16* H1 = XH + (size_t)n * 32;                 // n*64 halfs
  float*    S  = (float*)(H1 + (size_t)n * 64);       // n
  float*    T  = S + n;                               // n
  int* RP   = (int*)(T + n);                          // n+1 (pad 8)
  int* SSRC = RP + ((n + 8) & ~7);                    // E
  unsigned* BIN = (unsigned*)(SSRC + E);              // E (own buffer)
  int* CH   = (int*)(BIN + E);                        // 512
  int* CB   = CH + 512;                               // 520
  int* BCUR = CB + 520;                               // 512
  __half* WF1 = (__half*)(BCUR + 512);                // 4096 halfs
  __half* WF2 = WF1 + 4096;                           // 8192 halfs

  const int B = 256;
  const int nbuckets = (n + 255) >> NBSHIFT;          // 391
  const int ntiles = (E + TILE_A - 1) / TILE_A;       // 391
  const int gF = (n + 63) / 64;                       // 1563
  int n2 = n * 16;

  // 0) zero CH (2 KB, stream-ordered)
  hipMemsetAsync(CH, 0, 512 * sizeof(int), stream);
  // 1) per-tile hist -> CH | x->fp16 | weight frags
  k_prep<<<ntiles, B, 0, stream>>>(dst, (const float2*)x, (__half2*)XH,
                                   w1_rel, w1_root, w2_rel, w2_root,
                                   WF1, WF2, CH, E, n2, nbuckets);
  // 2) scan -> cb, bcur
  k_cscan<<<1, B, 0, stream>>>(CH, CB, BCUR, nbuckets, E);
  // 3) coarse binning
  k_binA<<<ntiles, B, 0, stream>>>(src, dst, BCUR, BIN, E, nbuckets);
  // 4) fine sort -> rp, ssrc
  k_fillB<<<nbuckets, B, 0, stream>>>(BIN, CB, RP, SSRC, n, E);
  // 5) layer 1 (1563 blocks — max TLP for the latency-bound gather)
  k_l1fused<<<gF, B, 0, stream>>>(XH, RP, SSRC, (const _Float16*)WF1, b1, H1, n);
  // 6) layer 2
  k_l2fused<<<gF, B, 0, stream>>>(H1, RP, SSRC, (const _Float16*)WF2,
                                  b2, w3_rel, w3_root, S, T, n);
  // 7) layer 3
  k_final<<<(4 * n + B - 1) / B, B, 0, stream>>>(S, RP, SSRC, T, b3, (float*)d_out, n);
}

// Round 18
// 135.754 us; speedup vs baseline: 1.0367x; 1.0367x over previous
//
#include <hip/hip_runtime.h>
#include <hip/hip_fp16.h>

typedef _Float16 f16x8 __attribute__((ext_vector_type(8)));
typedef float    f32x4 __attribute__((ext_vector_type(4)));

constexpr int DIN = 32;
constexpr int DH  = 64;
constexpr int NBSHIFT = 8;            // 256 nodes per coarse bucket
constexpr int TILE_A  = 4096;         // edges per phase-A block
constexpr int FB_CAP  = 6144;         // fillB LDS sort capacity

// ===================== fused setup: x->fp16, weight frags, zero CH ==========

__global__ __launch_bounds__(256) void k_setup(
    const float2* __restrict__ x2, __half2* __restrict__ xh,
    const float* __restrict__ w1_rel, const float* __restrict__ w1_root,
    const float* __restrict__ w2_rel, const float* __restrict__ w2_root,
    __half* __restrict__ wf1, __half* __restrict__ wf2,
    int* __restrict__ ch, int n2) {
  int i = blockIdx.x * 256 + threadIdx.x;
  if (i < n2) {
    float2 v = x2[i];
    xh[i] = __floats2half2_rn(v.x, v.y);
    return;
  }
  int u = i - n2;
  if (u < 512) {                      // W1 A-frags: k<32 w1_root, k>=32 w1_rel
    int lane = u & 63, kt = (u >> 6) & 1, mt = u >> 7;
    int out = 16 * mt + (lane & 15);
    int kb = 32 * kt + (lane >> 4) * 8;
    union { uint4 q; __half h[8]; } pk;
#pragma unroll
    for (int j = 0; j < 8; ++j) {
      int k = kb + j;
      float w = (k < 32) ? w1_root[k * DH + out] : w1_rel[(k - 32) * DH + out];
      pk.h[j] = __float2half(w);
    }
    *(uint4*)(wf1 + (size_t)u * 8) = pk.q;
    return;
  }
  u -= 512;
  if (u < 1024) {                     // W2 A-frags: k<64 w2_rel, k>=64 w2_root
    int lane = u & 63, kt = (u >> 6) & 3, mt = u >> 8;
    int out = 16 * mt + (lane & 15);
    int kb = 32 * kt + (lane >> 4) * 8;
    union { uint4 q; __half h[8]; } pk;
#pragma unroll
    for (int j = 0; j < 8; ++j) {
      int k = kb + j;
      float w = (k < 64) ? w2_rel[k * DH + out] : w2_root[(k - 64) * DH + out];
      pk.h[j] = __float2half(w);
    }
    *(uint4*)(wf2 + (size_t)u * 8) = pk.q;
    return;
  }
  u -= 1024;
  if (u < 512) ch[u] = 0;
}

// ===================== CSR build =====================

__global__ __launch_bounds__(256) void k_chist(
    const int* __restrict__ dst, int* __restrict__ ch, int E, int nbuckets) {
  __shared__ int hist[512];
  long long t0 = (long long)blockIdx.x * TILE_A;
  int cnt = (int)min((long long)TILE_A, (long long)E - t0);
  for (int i = threadIdx.x; i < nbuckets; i += 256) hist[i] = 0;
  __syncthreads();
  for (int r = threadIdx.x; r < cnt; r += 256)
    atomicAdd(&hist[dst[t0 + r] >> NBSHIFT], 1);
  __syncthreads();
  for (int i = threadIdx.x; i < nbuckets; i += 256)
    if (hist[i]) atomicAdd(&ch[i], hist[i]);
}

__global__ __launch_bounds__(256) void k_cscan(
    const int* __restrict__ ch, int* __restrict__ cb, int* __restrict__ bcur,
    int nbuckets, int E) {
  __shared__ int ts[256];
  int tid = threadIdx.x;
  int i0 = tid * 2, i1 = i0 + 1;
  int v0 = (i0 < nbuckets) ? ch[i0] : 0;
  int v1 = (i1 < nbuckets) ? ch[i1] : 0;
  int s = v0 + v1;
  ts[tid] = s;
  __syncthreads();
  for (int off = 1; off < 256; off <<= 1) {
    int val = (tid >= off) ? ts[tid - off] : 0;
    __syncthreads();
    ts[tid] += val;
    __syncthreads();
  }
  int ex = ts[tid] - s;
  if (i0 < nbuckets) { cb[i0] = ex;      bcur[i0] = ex; }
  if (i1 < nbuckets) { cb[i1] = ex + v0; bcur[i1] = ex + v0; }
  if (tid == 255) cb[nbuckets] = E;
}

// Phase A: bin edges into coarse buckets; LDS-sorted -> bucket-grouped writes.
__global__ __launch_bounds__(256) void k_binA(
    const int* __restrict__ src, const int* __restrict__ dst,
    int* __restrict__ bcur, unsigned* __restrict__ bin,
    int E, int nbuckets) {
  __shared__ int hist[512];
  __shared__ int lbase[512];
  __shared__ int gbase[512];
  __shared__ int ts[256];
  __shared__ unsigned lsort[TILE_A];
  __shared__ unsigned short lbuck[TILE_A];
  long long t0 = (long long)blockIdx.x * TILE_A;
  int cnt = (int)min((long long)TILE_A, (long long)E - t0);
  for (int i = threadIdx.x; i < 512; i += 256) hist[i] = 0;
  __syncthreads();
  unsigned pk[TILE_A / 256];
  int bo[TILE_A / 256];
#pragma unroll
  for (int q = 0; q < TILE_A / 256; ++q) {
    int r = (int)threadIdx.x + q * 256;
    if (r < cnt) {
      int d = dst[t0 + r];
      int s = src[t0 + r];
      int b = d >> NBSHIFT;
      int off = atomicAdd(&hist[b], 1);
      pk[q] = ((unsigned)(d & 255) << 17) | (unsigned)s;
      bo[q] = (b << 16) | off;
    }
  }
  __syncthreads();
  {
    int i0 = threadIdx.x * 2, i1 = i0 + 1;
    int v0 = hist[i0], v1 = hist[i1];
    int s2 = v0 + v1;
    ts[threadIdx.x] = s2;
    __syncthreads();
    for (int off = 1; off < 256; off <<= 1) {
      int val = (threadIdx.x >= off) ? ts[threadIdx.x - off] : 0;
      __syncthreads();
      ts[threadIdx.x] += val;
      __syncthreads();
    }
    int ex = ts[threadIdx.x] - s2;
    lbase[i0] = ex;
    lbase[i1] = ex + v0;
    gbase[i0] = v0 ? atomicAdd(&bcur[i0], v0) : 0;
    gbase[i1] = v1 ? atomicAdd(&bcur[i1], v1) : 0;
  }
  __syncthreads();
#pragma unroll
  for (int q = 0; q < TILE_A / 256; ++q) {
    int r = (int)threadIdx.x + q * 256;
    if (r < cnt) {
      int b = bo[q] >> 16, off = bo[q] & 0xFFFF;
      int li = lbase[b] + off;
      lsort[li] = pk[q];
      lbuck[li] = (unsigned short)b;
    }
  }
  __syncthreads();
  for (int i = threadIdx.x; i < cnt; i += 256) {
    int b = lbuck[i];
    bin[gbase[b] + (i - lbase[b])] = lsort[i];
  }
}

// Phase B: fine counting sort per bucket; coalesced ssrc writes via LDS.
__global__ __launch_bounds__(256) void k_fillB(
    const unsigned* __restrict__ bin, const int* __restrict__ cb,
    int* __restrict__ rp, int* __restrict__ ssrc, int n, int E) {
  __shared__ int deg[256];
  __shared__ int ts[256];
  __shared__ int cur[256];
  __shared__ int lsort[FB_CAP];
  int b = blockIdx.x;
  int nbase = b << NBSHIFT;
  int nn = min(256, n - nbase);
  int ebeg = cb[b], eend = cb[b + 1];
  int cnt = eend - ebeg;
  deg[threadIdx.x] = 0;
  __syncthreads();
  for (int e = ebeg + (int)threadIdx.x; e < eend; e += 256)
    atomicAdd(&deg[bin[e] >> 17], 1);
  __syncthreads();
  int d = deg[threadIdx.x];
  ts[threadIdx.x] = d;
  __syncthreads();
  for (int off = 1; off < 256; off <<= 1) {
    int val = (threadIdx.x >= off) ? ts[threadIdx.x - off] : 0;
    __syncthreads();
    ts[threadIdx.x] += val;
    __syncthreads();
  }
  int pref = ts[threadIdx.x] - d;
  if ((int)threadIdx.x < nn) rp[nbase + threadIdx.x] = ebeg + pref;
  if (b == 0 && threadIdx.x == 0) rp[n] = E;
  cur[threadIdx.x] = pref;
  __syncthreads();
  if (cnt <= FB_CAP) {
    for (int e = ebeg + (int)threadIdx.x; e < eend; e += 256) {
      unsigned u = bin[e];
      int pos = atomicAdd(&cur[u >> 17], 1);
      lsort[pos] = (int)(u & 0x1FFFF);
    }
    __syncthreads();
    for (int i = threadIdx.x; i < cnt; i += 256)
      ssrc[ebeg + i] = lsort[i];
  } else {
    for (int e = ebeg + (int)threadIdx.x; e < eend; e += 256) {
      unsigned u = bin[e];
      int pos = atomicAdd(&cur[u >> 17], 1);
      ssrc[ebeg + pos] = (int)(u & 0x1FFFF);
    }
  }
}

// ===================== layer 1 fused: gather(LDS) + MFMA =====================
__global__ __launch_bounds__(256) void k_l1fused(
    const _Float16* __restrict__ X, const int* __restrict__ rp,
    const int* __restrict__ ssrc, const _Float16* __restrict__ WF,
    const float* __restrict__ b1, _Float16* __restrict__ H1, int n) {
  __shared__ _Float16 sagg[64][40];
  int tid = threadIdx.x;
  int nl = tid >> 2;
  int unit = tid & 3;
  int nodeg = blockIdx.x * 64 + nl;
  {
    f16x8 accA = (f16x8)(_Float16)0.0f;
    f16x8 accB = (f16x8)(_Float16)0.0f;
    if (nodeg < n) {
      int beg = rp[nodeg], end = rp[nodeg + 1];
      const f16x8* fx = (const f16x8*)X;
      int e = beg;
      for (; e + 7 < end; e += 8) {
        int s0 = ssrc[e],     s1 = ssrc[e + 1], s2 = ssrc[e + 2], s3 = ssrc[e + 3];
        int s4 = ssrc[e + 4], s5 = ssrc[e + 5], s6 = ssrc[e + 6], s7 = ssrc[e + 7];
        f16x8 v0 = fx[(size_t)s0 * 4 + unit];
        f16x8 v1 = fx[(size_t)s1 * 4 + unit];
        f16x8 v2 = fx[(size_t)s2 * 4 + unit];
        f16x8 v3 = fx[(size_t)s3 * 4 + unit];
        f16x8 v4 = fx[(size_t)s4 * 4 + unit];
        f16x8 v5 = fx[(size_t)s5 * 4 + unit];
        f16x8 v6 = fx[(size_t)s6 * 4 + unit];
        f16x8 v7 = fx[(size_t)s7 * 4 + unit];
        accA += v0; accB += v1; accA += v2; accB += v3;
        accA += v4; accB += v5; accA += v6; accB += v7;
      }
      for (; e + 1 < end; e += 2) {
        int s0 = ssrc[e], s1 = ssrc[e + 1];
        f16x8 v0 = fx[(size_t)s0 * 4 + unit];
        f16x8 v1 = fx[(size_t)s1 * 4 + unit];
        accA += v0; accB += v1;
      }
      if (e < end) accA += fx[(size_t)ssrc[e] * 4 + unit];
    }
    *(f16x8*)&sagg[nl][unit * 8] = accA + accB;
  }
  __syncthreads();
  int lane = tid & 63;
  int w = tid >> 6;
  int nl16 = w * 16 + (lane & 15);
  int node = blockIdx.x * 64 + nl16;
  int nodeld = min(node, n - 1);
  f16x8 bf0 = *(const f16x8*)(X + (size_t)nodeld * 32 + (lane >> 4) * 8);
  f16x8 bf1 = *(const f16x8*)&sagg[nl16][(lane >> 4) * 8];
  const f16x8* ap = (const f16x8*)WF + lane;
  f32x4 acc[4];
#pragma unroll
  for (int mt = 0; mt < 4; ++mt) acc[mt] = (f32x4)(0.f);
#pragma unroll
  for (int mt = 0; mt < 4; ++mt) {
    acc[mt] = __builtin_amdgcn_mfma_f32_16x16x32_f16(ap[(mt * 2 + 0) * 64], bf0, acc[mt], 0, 0, 0);
    acc[mt] = __builtin_amdgcn_mfma_f32_16x16x32_f16(ap[(mt * 2 + 1) * 64], bf1, acc[mt], 0, 0, 0);
  }
  if (node >= n) return;
  int jb = (lane >> 4) * 4;
  _Float16* op = H1 + (size_t)node * 64 + jb;
#pragma unroll
  for (int mt = 0; mt < 4; ++mt) {
    f32x4 vb = *(const f32x4*)(b1 + 16 * mt + jb);
    union { uint2 u2; _Float16 h[4]; } pko;
#pragma unroll
    for (int r = 0; r < 4; ++r)
      pko.h[r] = (_Float16)fmaxf(acc[mt][r] + vb[r], 0.f);
    *(uint2*)(op + 16 * mt) = pko.u2;
  }
}

// ===================== layer 2 fused: gather(LDS) + MFMA + proj =============
__global__ __launch_bounds__(256) void k_l2fused(
    const _Float16* __restrict__ H1, const int* __restrict__ rp,
    const int* __restrict__ ssrc, const _Float16* __restrict__ WF,
    const float* __restrict__ b2, const float* __restrict__ w3rel,
    const float* __restrict__ w3root,
    float* __restrict__ S, float* __restrict__ T, int n) {
  __shared__ _Float16 sagg[64][72];
  int tid = threadIdx.x;
  int nl = tid >> 2;
  int u0 = tid & 3;
  int nodeg = blockIdx.x * 64 + nl;
  {
    f16x8 aA = (f16x8)(_Float16)0.0f, aB = (f16x8)(_Float16)0.0f;
    f16x8 cA = (f16x8)(_Float16)0.0f, cB = (f16x8)(_Float16)0.0f;
    if (nodeg < n) {
      int beg = rp[nodeg], end = rp[nodeg + 1];
      const f16x8* fh = (const f16x8*)H1;
      int e = beg;
      for (; e + 7 < end; e += 8) {
        int s0 = ssrc[e],     s1 = ssrc[e + 1], s2 = ssrc[e + 2], s3 = ssrc[e + 3];
        int s4 = ssrc[e + 4], s5 = ssrc[e + 5], s6 = ssrc[e + 6], s7 = ssrc[e + 7];
        f16x8 a0 = fh[(size_t)s0 * 8 + u0];
        f16x8 c0 = fh[(size_t)s0 * 8 + u0 + 4];
        f16x8 a1 = fh[(size_t)s1 * 8 + u0];
        f16x8 c1 = fh[(size_t)s1 * 8 + u0 + 4];
        f16x8 a2 = fh[(size_t)s2 * 8 + u0];
        f16x8 c2 = fh[(size_t)s2 * 8 + u0 + 4];
        f16x8 a3 = fh[(size_t)s3 * 8 + u0];
        f16x8 c3 = fh[(size_t)s3 * 8 + u0 + 4];
        f16x8 a4 = fh[(size_t)s4 * 8 + u0];
        f16x8 c4 = fh[(size_t)s4 * 8 + u0 + 4];
        f16x8 a5 = fh[(size_t)s5 * 8 + u0];
        f16x8 c5 = fh[(size_t)s5 * 8 + u0 + 4];
        f16x8 a6 = fh[(size_t)s6 * 8 + u0];
        f16x8 c6 = fh[(size_t)s6 * 8 + u0 + 4];
        f16x8 a7 = fh[(size_t)s7 * 8 + u0];
        f16x8 c7 = fh[(size_t)s7 * 8 + u0 + 4];
        aA += a0; cA += c0; aB += a1; cB += c1;
        aA += a2; cA += c2; aB += a3; cB += c3;
        aA += a4; cA += c4; aB += a5; cB += c5;
        aA += a6; cA += c6; aB += a7; cB += c7;
      }
      for (; e + 1 < end; e += 2) {
        int s0 = ssrc[e], s1 = ssrc[e + 1];
        aA += fh[(size_t)s0 * 8 + u0];
        cA += fh[(size_t)s0 * 8 + u0 + 4];
        aB += fh[(size_t)s1 * 8 + u0];
        cB += fh[(size_t)s1 * 8 + u0 + 4];
      }
      if (e < end) {
        int s0 = ssrc[e];
        aA += fh[(size_t)s0 * 8 + u0];
        cA += fh[(size_t)s0 * 8 + u0 + 4];
      }
    }
    *(f16x8*)&sagg[nl][u0 * 8] = aA + aB;
    *(f16x8*)&sagg[nl][(u0 + 4) * 8] = cA + cB;
  }
  __syncthreads();
  int lane = tid & 63;
  int w = tid >> 6;
  int nl16 = w * 16 + (lane & 15);
  int node = blockIdx.x * 64 + nl16;
  int nodeld = min(node, n - 1);
  f16x8 bf[4];
  bf[0] = *(const f16x8*)&sagg[nl16][(lane >> 4) * 8];
  bf[1] = *(const f16x8*)&sagg[nl16][32 + (lane >> 4) * 8];
  bf[2] = *(const f16x8*)(H1 + (size_t)nodeld * 64 + (lane >> 4) * 8);
  bf[3] = *(const f16x8*)(H1 + (size_t)nodeld * 64 + 32 + (lane >> 4) * 8);
  const f16x8* ap = (const f16x8*)WF + lane;
  f32x4 acc[4];
#pragma unroll
  for (int mt = 0; mt < 4; ++mt) acc[mt] = (f32x4)(0.f);
#pragma unroll
  for (int mt = 0; mt < 4; ++mt)
#pragma unroll
    for (int kt = 0; kt < 4; ++kt)
      acc[mt] = __builtin_amdgcn_mfma_f32_16x16x32_f16(
          ap[(mt * 4 + kt) * 64], bf[kt], acc[mt], 0, 0, 0);
  int jb = (lane >> 4) * 4;
  float s = 0.f, t = 0.f;
#pragma unroll
  for (int mt = 0; mt < 4; ++mt) {
    f32x4 vb = *(const f32x4*)(b2 + 16 * mt + jb);
    f32x4 vr = *(const f32x4*)(w3rel + 16 * mt + jb);
    f32x4 vt = *(const f32x4*)(w3root + 16 * mt + jb);
#pragma unroll
    for (int r = 0; r < 4; ++r) {
      float h = fmaxf(acc[mt][r] + vb[r], 0.f);
      s = fmaf(h, vr[r], s);
      t = fmaf(h, vt[r], t);
    }
  }
  s += __shfl_xor(s, 16); s += __shfl_xor(s, 32);
  t += __shfl_xor(t, 16); t += __shfl_xor(t, 32);
  if (lane < 16 && node < n) { S[node] = s; T[node] = t; }
}

// ===================== final: out = segsum(S) + b3 + T (4 lanes/node) =======

__global__ __launch_bounds__(256) void k_final(
    const float* __restrict__ sv, const int* __restrict__ rp,
    const int* __restrict__ ssrc, const float* __restrict__ T,
    const float* __restrict__ b3, float* __restrict__ out, int n) {
  int t = blockIdx.x * 256 + threadIdx.x;
  int node = t >> 2;
  int l = t & 3;
  if (node >= n) return;
  int beg = rp[node], end = rp[node + 1];
  float a = 0.f;
  for (int e = beg + l; e < end; e += 4) a += sv[ssrc[e]];
  a += __shfl_xor(a, 1);
  a += __shfl_xor(a, 2);
  if (l == 0) out[node] = a + b3[0] + T[node];
}

// ===================== launch =====================

extern "C" void kernel_launch(void* const* d_in, const int* in_sizes, int n_in,
                              void* d_out, int out_size, void* d_ws, size_t ws_size,
                              hipStream_t stream) {
  const float* x       = (const float*)d_in[0];
  const float* w1_rel  = (const float*)d_in[1];
  const float* b1      = (const float*)d_in[2];
  const float* w1_root = (const float*)d_in[3];
  const float* w2_rel  = (const float*)d_in[4];
  const float* b2      = (const float*)d_in[5];
  const float* w2_root = (const float*)d_in[6];
  const float* w3_rel  = (const float*)d_in[7];
  const float* b3      = (const float*)d_in[8];
  const float* w3_root = (const float*)d_in[9];
  const int*   edge    = (const int*)d_in[10];

  const int n = in_sizes[0] / DIN;        // 100000 (< 2^17 for packing)
  const int E = in_sizes[10] / 2;         // 1600000
  const int* src = edge;
  const int* dst = edge + E;

  _Float16* XH = (_Float16*)d_ws;                     // n*32 halfs (x fp16)
  _Float16* H1 = XH + (size_t)n * 32;                 // n*64 halfs (h1)
  float*    S  = (float*)(H1 + (size_t)n * 64);       // n
  float*    T  = S + n;                               // n
  int* RP   = (int*)(T + n);                          // n+1 (pad to 8)
  int* SSRC = RP + ((n + 8) & ~7);                    // E
  int* CH   = SSRC + E;                               // 512
  int* CB   = CH + 512;                               // 513 (pad 520)
  int* BCUR = CB + 520;                               // 512
  __half* WF1 = (__half*)(BCUR + 512);                // 4096 halfs
  __half* WF2 = WF1 + 4096;                           // 8192 halfs
  unsigned* BIN = (unsigned*)H1;                      // E (dead before H1 writes)

  const int B = 256;
  const int nbuckets = (n + 255) >> NBSHIFT;          // 391
  const int gA = (E + TILE_A - 1) / TILE_A;           // 391
  const int gF = (n + 63) / 64;                       // fused-layer blocks

  // setup: x->fp16 | W1 frags | W2 frags | zero CH
  {
    int n2 = n * 16;
    int tot = n2 + 2048;
    k_setup<<<(tot + B - 1) / B, B, 0, stream>>>(
        (const float2*)x, (__half2*)XH, w1_rel, w1_root, w2_rel, w2_root,
        WF1, WF2, CH, n2);
  }

  // CSR build
  k_chist<<<gA, B, 0, stream>>>(dst, CH, E, nbuckets);
  k_cscan<<<1, B, 0, stream>>>(CH, CB, BCUR, nbuckets, E);
  k_binA<<<gA, B, 0, stream>>>(src, dst, BCUR, BIN, E, nbuckets);
  k_fillB<<<nbuckets, B, 0, stream>>>(BIN, CB, RP, SSRC, n, E);

  // layers (gather fused with MFMA; agg in LDS, packed-fp16 accumulate)
  k_l1fused<<<gF, B, 0, stream>>>(XH, RP, SSRC, (const _Float16*)WF1, b1, H1, n);
  k_l2fused<<<gF, B, 0, stream>>>(H1, RP, SSRC, (const _Float16*)WF2,
                                  b2, w3_rel, w3_root, S, T, n);

  // layer 3
  k_final<<<(4 * n + B - 1) / B, B, 0, stream>>>(S, RP, SSRC, T, b3, (float*)d_out, n);
}